// Round 16
// baseline (96.352 us; speedup 1.0000x reference)
//
#include <hip/hip_runtime.h>
#include <hip/hip_fp16.h>
#include <math.h>

#define NEG_SLOPE 0.2f
#define QINV 15.875f               /* 127/8 */
#define SCALE_G 0.06299212598f     /* 8/127 */

typedef _Float16 f16x2 __attribute__((ext_vector_type(2)));
typedef _Float16 f16x8 __attribute__((ext_vector_type(8)));
typedef float f32x4 __attribute__((ext_vector_type(4)));

__device__ __forceinline__ float fdot2f(unsigned int a, unsigned int b, float c) {
#if __has_builtin(__builtin_amdgcn_fdot2)
    return __builtin_amdgcn_fdot2(__builtin_bit_cast(f16x2, a),
                                  __builtin_bit_cast(f16x2, b), c, false);
#else
    __half2 ah = __builtin_bit_cast(__half2, a), bh = __builtin_bit_cast(__half2, b);
    float2 af = __half22float2(ah), bf = __half22float2(bh);
    return c + af.x * bf.x + af.y * bf.y;
#endif
}

__device__ __forceinline__ unsigned int packw(float a, float b) {
#if __has_builtin(__builtin_amdgcn_cvt_pkrtz)
    return __builtin_bit_cast(unsigned int, __builtin_amdgcn_cvt_pkrtz(a, b));
#else
    return __builtin_bit_cast(unsigned int, __floats2half2_rn(a, b));
#endif
}

// ---------------------------------------------------------------------------
// Kernel 0: fused prep (blocks 0..63: W->fp16 transpose + attn vecs) +
// segment offsets (blocks 64..).
// ---------------------------------------------------------------------------
__global__ __launch_bounds__(256) void prep_seg_kernel(
    const float* __restrict__ W, __half* __restrict__ w16t,
    const float* __restrict__ attn_l, const float* __restrict__ attn_r,
    __half* __restrict__ al16, __half* __restrict__ ar16,
    const int* __restrict__ dst, int* __restrict__ off, int E, int N)
{
    const int b = blockIdx.x;
    if (b < 64) {
        int tid = b * 256 + threadIdx.x;
        int c = tid >> 7, k = tid & 127;
        w16t[c * 128 + k] = __float2half(W[k * 128 + c]);
        if (tid < 128) {
            al16[tid] = __float2half(attn_l[tid]);
            ar16[tid] = __float2half(attn_r[tid]);
        }
        return;
    }
    int i = (b - 64) * 256 + threadIdx.x;
    if (i >= E) return;
    int d = dst[i];
    int prev = (i == 0) ? -1 : dst[i - 1];
    for (int n = prev + 1; n <= d; ++n) off[n] = i;
    if (i == E - 1) {
        for (int n = d + 1; n <= N; ++n) off[n] = E;
    }
}

// ---------------------------------------------------------------------------
// Kernel 1: proj — 128x128 tile, 512 thr, MFMA 16x16x32_f16. Epilogue:
// repack to LDS row-major, el/er via LDS reads (coalesced stores), then
// i8 quant with FIXED global scale 8/127 (biased bytes b=q+128).
// ---------------------------------------------------------------------------
__global__ __launch_bounds__(512) void proj_kernel(
    const float* __restrict__ h, const __half* __restrict__ w16t,
    const __half* __restrict__ al16, const __half* __restrict__ ar16,
    unsigned char* __restrict__ feat8, float* __restrict__ el,
    float* __restrict__ er, int N)
{
    __shared__ __half hl[128 * 128];              // h tile, later out tile
    __shared__ __half wl[128 * 128];
    const int t = threadIdx.x;
    const int nodeBase = blockIdx.x * 128;

#pragma unroll
    for (int i = 0; i < 4; ++i) {
        int ch = t + i * 512;                     // 2048 16B chunks
        int col = ch >> 4, k8 = ch & 15;
        uint4 v = *(const uint4*)(w16t + col * 128 + k8 * 8);
        int byte = col * 256 + k8 * 16;
        *(uint4*)((char*)wl + (byte ^ ((col & 7) << 4))) = v;
    }
#pragma unroll
    for (int i = 0; i < 8; ++i) {
        int slot = t + i * 512;                   // 4096 float4 slots
        int row = slot >> 5, c4 = slot & 31;
        int gn = nodeBase + row;
        float4 v = make_float4(0.f, 0.f, 0.f, 0.f);
        if (gn < N) v = *(const float4*)(h + (size_t)gn * 128 + c4 * 4);
        __half2 p0 = __floats2half2_rn(v.x, v.y);
        __half2 p1 = __floats2half2_rn(v.z, v.w);
        uint2 u = make_uint2(__builtin_bit_cast(unsigned int, p0),
                             __builtin_bit_cast(unsigned int, p1));
        int byte = row * 256 + c4 * 8;
        *(uint2*)((char*)hl + (byte ^ ((row & 7) << 4))) = u;
    }
    __syncthreads();

    const int l = t & 63, wave = t >> 6;
    const int arow = wave * 16 + (l & 15);
    const int kg = l >> 4;
    f32x4 acc[8];
#pragma unroll
    for (int i = 0; i < 8; ++i) acc[i] = (f32x4){0.f, 0.f, 0.f, 0.f};

#pragma unroll
    for (int kt = 0; kt < 4; ++kt) {
        const int kb = (kt * 32 + kg * 8) * 2;
        f16x8 a = *(const f16x8*)((const char*)hl +
                    ((arow * 256 + kb) ^ ((arow & 7) << 4)));
#pragma unroll
        for (int ct = 0; ct < 8; ++ct) {
            int bcol = ct * 16 + (l & 15);
            f16x8 b = *(const f16x8*)((const char*)wl +
                        ((bcol * 256 + kb) ^ ((bcol & 7) << 4)));
            acc[ct] = __builtin_amdgcn_mfma_f32_16x16x32_f16(a, b, acc[ct], 0, 0, 0);
        }
    }

    __syncthreads();
    const int colLo = l & 15;
    const int rowHi = wave * 16 + (l >> 4) * 4;
#pragma unroll
    for (int ct = 0; ct < 8; ++ct) {
#pragma unroll
        for (int r = 0; r < 4; ++r) {
            int row = rowHi + r;
            int byte = row * 256 + (ct * 16 + colLo) * 2;
            *(__half*)((char*)hl + (byte ^ ((row & 7) << 4))) = __float2half(acc[ct][r]);
        }
    }
    __syncthreads();                              // tile complete

    // ---- el/er from LDS: thread = (row=t>>2, head=t&3); coalesced stores
    {
        const int row = t >> 2, head = t & 3;
        const int node = nodeBase + row;
        float lv = 0.f, rv = 0.f;
#pragma unroll
        for (int j = 0; j < 4; ++j) {
            int byte = row * 256 + head * 64 + j * 16;
            uint4 f = *(const uint4*)((const char*)hl + (byte ^ ((row & 7) << 4)));
            uint4 a = *(const uint4*)(al16 + head * 32 + j * 8);
            uint4 bb = *(const uint4*)(ar16 + head * 32 + j * 8);
            lv = fdot2f(f.x, a.x, lv); rv = fdot2f(f.x, bb.x, rv);
            lv = fdot2f(f.y, a.y, lv); rv = fdot2f(f.y, bb.y, rv);
            lv = fdot2f(f.z, a.z, lv); rv = fdot2f(f.z, bb.z, rv);
            lv = fdot2f(f.w, a.w, lv); rv = fdot2f(f.w, bb.w, rv);
        }
        if (node < N) {
            el[(size_t)node * 4 + head] = lv;
            er[(size_t)node * 4 + head] = rv;
        }
    }

    // ---- i8 quant, fixed scale: thread = (row=t>>2, quarter=t&3)
    {
        const int r = t >> 2, q = t & 3;
        const int node = nodeBase + r;
        unsigned int outw[8];
#pragma unroll
        for (int j = 0; j < 4; ++j) {
            int ch = r * 16 + q * 4 + j;
            uint4 c4 = *(const uint4*)((const char*)hl + ((ch * 16) ^ ((r & 7) << 4)));
            const __half2* hp = (const __half2*)&c4;
#pragma unroll
            for (int u = 0; u < 2; ++u) {
                float2 fa = __half22float2(hp[2 * u]);
                float2 fb = __half22float2(hp[2 * u + 1]);
                unsigned i0 = (unsigned)(min(max(__float2int_rn(fa.x * QINV), -128), 127) + 128);
                unsigned i1 = (unsigned)(min(max(__float2int_rn(fa.y * QINV), -128), 127) + 128);
                unsigned i2 = (unsigned)(min(max(__float2int_rn(fb.x * QINV), -128), 127) + 128);
                unsigned i3 = (unsigned)(min(max(__float2int_rn(fb.y * QINV), -128), 127) + 128);
                outw[j * 2 + u] = i0 | (i1 << 8) | (i2 << 16) | (i3 << 24);
            }
        }
        if (node < N) {
            uint4* d4 = (uint4*)(feat8 + (size_t)node * 128 + q * 32);
            d4[0] = make_uint4(outw[0], outw[1], outw[2], outw[3]);
            d4[1] = make_uint4(outw[4], outw[5], outw[6], outw[7]);
        }
    }
}

// ---------------------------------------------------------------------------
// Kernel 2: fused aggregate on biased-i8 feat. r15's loop shape, but edge
// weights computed inline via r9's cooperative scheme: per 16-edge batch,
// lane c handles edge ei+(c>>2), head (c&3) -> 1 el-gather (L2-resident)
// + 1 exp per lane; pairs redistributed by 2 shfl + cvt_pkrtz. Deletes
// the edgew kernel and all w_t traffic.
// ---------------------------------------------------------------------------
__global__ __launch_bounds__(256) void aggregate_kernel(
    const unsigned char* __restrict__ feat8, const float* __restrict__ el,
    const float* __restrict__ er, const int* __restrict__ off,
    const int* __restrict__ src, const float* __restrict__ bias,
    float* __restrict__ out, int N)
{
    const int wid = (int)((blockIdx.x * blockDim.x + threadIdx.x) >> 6);
    const int l = threadIdx.x & 63;
    if (wid >= N) return;
    const int n = __builtin_amdgcn_readfirstlane(wid);   // SGPR node id
    const int s = off[n];                                // s_load
    const int e = off[n + 1];                            // s_load
    const int f0 = 2 * l;
    const int hm = l >> 4;
    const float b0 = bias[f0], b1 = bias[f0 + 1];
    float* outp = out + (size_t)n * 128;
    if (s >= e) {
        outp[f0] = fmaxf(b0, 0.f);
        outp[f0 + 1] = fmaxf(b1, 0.f);
        return;
    }

    const float er_mine = er[n * 4 + hm];                // tail path
    const float er_coop = er[n * 4 + (l & 3)];           // cooperative path
    float ax = 0.f, ay = 0.f, dn = 0.f;
    const unsigned int one2 = 0x3C003C00u;
    const unsigned int bias2 = 0x66006600u;

    int ei = s;
    for (; ei + 16 <= e; ei += 16) {
        int sv[16];
#pragma unroll
        for (int k = 0; k < 16; ++k) sv[k] = src[ei + k];        // s_loads
        // cooperative w: lane c -> edge ei+(c>>2), head (c&3)
        int svc = src[ei + (l >> 2)];
        float sc = el[(size_t)svc * 4 + (l & 3)] + er_coop;      // L2-resident
        sc = sc > 0.f ? sc : NEG_SLOPE * sc;
        float myw = __expf(sc);
        unsigned int g[16];
#pragma unroll
        for (int k = 0; k < 16; ++k)
            g[k] = *(const unsigned short*)(feat8 + (size_t)sv[k] * 128 + f0);
#pragma unroll
        for (int k = 0; k < 8; ++k) {
            float wa = __shfl(myw, 8 * k + hm);          // w(edge 2k, head hm)
            float wb = __shfl(myw, 8 * k + 4 + hm);      // w(edge 2k+1, head hm)
            unsigned int w2 = packw(wa, wb);
            unsigned int comb = g[2 * k] | (g[2 * k + 1] << 16);
            unsigned int ux = (comb & 0x00FF00FFu) | bias2;
            unsigned int uy = ((comb >> 8) & 0x00FF00FFu) | bias2;
            ax = fdot2f(w2, ux, ax);
            ay = fdot2f(w2, uy, ay);
            dn = fdot2f(w2, one2, dn);
        }
    }
    if (ei + 8 <= e) {
        int sv[8];
#pragma unroll
        for (int k = 0; k < 8; ++k) sv[k] = src[ei + k];
        int svc = src[ei + ((l >> 2) & 7)];              // lanes 0..31 cover 8 edges
        float sc = el[(size_t)svc * 4 + (l & 3)] + er_coop;
        sc = sc > 0.f ? sc : NEG_SLOPE * sc;
        float myw = __expf(sc);
        unsigned int g[8];
#pragma unroll
        for (int k = 0; k < 8; ++k)
            g[k] = *(const unsigned short*)(feat8 + (size_t)sv[k] * 128 + f0);
#pragma unroll
        for (int k = 0; k < 4; ++k) {
            float wa = __shfl(myw, 8 * k + hm);
            float wb = __shfl(myw, 8 * k + 4 + hm);
            unsigned int w2 = packw(wa, wb);
            unsigned int comb = g[2 * k] | (g[2 * k + 1] << 16);
            unsigned int ux = (comb & 0x00FF00FFu) | bias2;
            unsigned int uy = ((comb >> 8) & 0x00FF00FFu) | bias2;
            ax = fdot2f(w2, ux, ax);
            ay = fdot2f(w2, uy, ay);
            dn = fdot2f(w2, one2, dn);
        }
        ei += 8;
    }
    for (; ei < e; ++ei) {                               // <=7 tail edges
        int sv = src[ei];
        float sc = el[(size_t)sv * 4 + hm] + er_mine;
        sc = sc > 0.f ? sc : NEG_SLOPE * sc;
        float w = __expf(sc);
        unsigned int gg = *(const unsigned short*)(feat8 + (size_t)sv * 128 + f0);
        ax += w * (float)(1536 + (gg & 0xFF));
        ay += w * (float)(1536 + (gg >> 8));
        dn += w;
    }
    const float inv = 1.f / dn;
    const float rx = SCALE_G * (ax * inv - 1664.f) + b0;
    const float ry = SCALE_G * (ay * inv - 1664.f) + b1;
    *(float2*)(outp + f0) = make_float2(fmaxf(rx, 0.f), fmaxf(ry, 0.f));
}

// ---------------------------------------------------------------------------
extern "C" void kernel_launch(void* const* d_in, const int* in_sizes, int n_in,
                              void* d_out, int out_size, void* d_ws, size_t ws_size,
                              hipStream_t stream)
{
    const float* h      = (const float*)d_in[0];
    const int*   src    = (const int*)d_in[1];
    const int*   dst    = (const int*)d_in[2];
    const float* W      = (const float*)d_in[3];
    const float* attn_l = (const float*)d_in[4];
    const float* attn_r = (const float*)d_in[5];
    const float* bias   = (const float*)d_in[6];
    const int N = in_sizes[0] / 128;
    const int E = in_sizes[1];
    float* out = (float*)d_out;

    // workspace (all offsets multiples of 16B)
    char* ws = (char*)d_ws;
    unsigned char* feat8 = (unsigned char*)ws; ws += (size_t)N * 128;              // 12.8MB
    float*  el   = (float*)ws;             ws += (size_t)N * 4 * sizeof(float);    // 1.6MB
    float*  er   = (float*)ws;             ws += (size_t)N * 4 * sizeof(float);    // 1.6MB
    __half* w16t = (__half*)ws;            ws += 128 * 128 * sizeof(__half);       // 32KB
    __half* al16 = (__half*)ws;            ws += 256;
    __half* ar16 = (__half*)ws;            ws += 256;
    int*    off  = (int*)ws;

    hipLaunchKernelGGL(prep_seg_kernel, dim3(64 + (E + 255) / 256), dim3(256), 0, stream,
                       W, w16t, attn_l, attn_r, al16, ar16, dst, off, E, N);
    hipLaunchKernelGGL(proj_kernel, dim3((N + 127) / 128), dim3(512), 0, stream,
                       h, w16t, al16, ar16, feat8, el, er, N);
    hipLaunchKernelGGL(aggregate_kernel, dim3((N + 3) / 4), dim3(256), 0, stream,
                       feat8, el, er, off, src, bias, out, N);
}

// Round 17
// 90.161 us; speedup vs baseline: 1.0687x; 1.0687x over previous
//
#include <hip/hip_runtime.h>
#include <hip/hip_fp16.h>
#include <math.h>

#define NEG_SLOPE 0.2f
#define QINV 15.875f               /* 127/8 */
#define SCALE_G 0.06299212598f     /* 8/127 */

typedef _Float16 f16x2 __attribute__((ext_vector_type(2)));
typedef _Float16 f16x8 __attribute__((ext_vector_type(8)));
typedef float f32x4 __attribute__((ext_vector_type(4)));

__device__ __forceinline__ float fdot2f(unsigned int a, unsigned int b, float c) {
#if __has_builtin(__builtin_amdgcn_fdot2)
    return __builtin_amdgcn_fdot2(__builtin_bit_cast(f16x2, a),
                                  __builtin_bit_cast(f16x2, b), c, false);
#else
    __half2 ah = __builtin_bit_cast(__half2, a), bh = __builtin_bit_cast(__half2, b);
    float2 af = __half22float2(ah), bf = __half22float2(bh);
    return c + af.x * bf.x + af.y * bf.y;
#endif
}

// ---------------------------------------------------------------------------
// Kernel 0: fused prep (blocks 0..63: W->fp16 transpose + attn vecs) +
// segment offsets (blocks 64..).
// ---------------------------------------------------------------------------
__global__ __launch_bounds__(256) void prep_seg_kernel(
    const float* __restrict__ W, __half* __restrict__ w16t,
    const float* __restrict__ attn_l, const float* __restrict__ attn_r,
    __half* __restrict__ al16, __half* __restrict__ ar16,
    const int* __restrict__ dst, int* __restrict__ off, int E, int N)
{
    const int b = blockIdx.x;
    if (b < 64) {
        int tid = b * 256 + threadIdx.x;
        int c = tid >> 7, k = tid & 127;
        w16t[c * 128 + k] = __float2half(W[k * 128 + c]);
        if (tid < 128) {
            al16[tid] = __float2half(attn_l[tid]);
            ar16[tid] = __float2half(attn_r[tid]);
        }
        return;
    }
    int i = (b - 64) * 256 + threadIdx.x;
    if (i >= E) return;
    int d = dst[i];
    int prev = (i == 0) ? -1 : dst[i - 1];
    for (int n = prev + 1; n <= d; ++n) off[n] = i;
    if (i == E - 1) {
        for (int n = d + 1; n <= N; ++n) off[n] = E;
    }
}

// ---------------------------------------------------------------------------
// Kernel 1: proj — 128x128 tile, 512 thr, MFMA 16x16x32_f16. Epilogue:
// repack to LDS row-major, el/er via LDS reads (coalesced stores), then
// i8 quant with FIXED global scale 8/127 (biased bytes b=q+128; no row
// max-scan, no scale array).
// ---------------------------------------------------------------------------
__global__ __launch_bounds__(512) void proj_kernel(
    const float* __restrict__ h, const __half* __restrict__ w16t,
    const __half* __restrict__ al16, const __half* __restrict__ ar16,
    unsigned char* __restrict__ feat8, float* __restrict__ el,
    float* __restrict__ er, int N)
{
    __shared__ __half hl[128 * 128];              // h tile, later out tile
    __shared__ __half wl[128 * 128];
    const int t = threadIdx.x;
    const int nodeBase = blockIdx.x * 128;

#pragma unroll
    for (int i = 0; i < 4; ++i) {
        int ch = t + i * 512;                     // 2048 16B chunks
        int col = ch >> 4, k8 = ch & 15;
        uint4 v = *(const uint4*)(w16t + col * 128 + k8 * 8);
        int byte = col * 256 + k8 * 16;
        *(uint4*)((char*)wl + (byte ^ ((col & 7) << 4))) = v;
    }
#pragma unroll
    for (int i = 0; i < 8; ++i) {
        int slot = t + i * 512;                   // 4096 float4 slots
        int row = slot >> 5, c4 = slot & 31;
        int gn = nodeBase + row;
        float4 v = make_float4(0.f, 0.f, 0.f, 0.f);
        if (gn < N) v = *(const float4*)(h + (size_t)gn * 128 + c4 * 4);
        __half2 p0 = __floats2half2_rn(v.x, v.y);
        __half2 p1 = __floats2half2_rn(v.z, v.w);
        uint2 u = make_uint2(__builtin_bit_cast(unsigned int, p0),
                             __builtin_bit_cast(unsigned int, p1));
        int byte = row * 256 + c4 * 8;
        *(uint2*)((char*)hl + (byte ^ ((row & 7) << 4))) = u;
    }
    __syncthreads();

    const int l = t & 63, wave = t >> 6;
    const int arow = wave * 16 + (l & 15);
    const int kg = l >> 4;
    f32x4 acc[8];
#pragma unroll
    for (int i = 0; i < 8; ++i) acc[i] = (f32x4){0.f, 0.f, 0.f, 0.f};

#pragma unroll
    for (int kt = 0; kt < 4; ++kt) {
        const int kb = (kt * 32 + kg * 8) * 2;
        f16x8 a = *(const f16x8*)((const char*)hl +
                    ((arow * 256 + kb) ^ ((arow & 7) << 4)));
#pragma unroll
        for (int ct = 0; ct < 8; ++ct) {
            int bcol = ct * 16 + (l & 15);
            f16x8 b = *(const f16x8*)((const char*)wl +
                        ((bcol * 256 + kb) ^ ((bcol & 7) << 4)));
            acc[ct] = __builtin_amdgcn_mfma_f32_16x16x32_f16(a, b, acc[ct], 0, 0, 0);
        }
    }

    __syncthreads();
    const int colLo = l & 15;
    const int rowHi = wave * 16 + (l >> 4) * 4;
#pragma unroll
    for (int ct = 0; ct < 8; ++ct) {
#pragma unroll
        for (int r = 0; r < 4; ++r) {
            int row = rowHi + r;
            int byte = row * 256 + (ct * 16 + colLo) * 2;
            *(__half*)((char*)hl + (byte ^ ((row & 7) << 4))) = __float2half(acc[ct][r]);
        }
    }
    __syncthreads();                              // tile complete

    // ---- el/er from LDS: thread = (row=t>>2, head=t&3); coalesced stores
    {
        const int row = t >> 2, head = t & 3;
        const int node = nodeBase + row;
        float lv = 0.f, rv = 0.f;
#pragma unroll
        for (int j = 0; j < 4; ++j) {
            int byte = row * 256 + head * 64 + j * 16;
            uint4 f = *(const uint4*)((const char*)hl + (byte ^ ((row & 7) << 4)));
            uint4 a = *(const uint4*)(al16 + head * 32 + j * 8);
            uint4 bb = *(const uint4*)(ar16 + head * 32 + j * 8);
            lv = fdot2f(f.x, a.x, lv); rv = fdot2f(f.x, bb.x, rv);
            lv = fdot2f(f.y, a.y, lv); rv = fdot2f(f.y, bb.y, rv);
            lv = fdot2f(f.z, a.z, lv); rv = fdot2f(f.z, bb.z, rv);
            lv = fdot2f(f.w, a.w, lv); rv = fdot2f(f.w, bb.w, rv);
        }
        if (node < N) {
            el[(size_t)node * 4 + head] = lv;
            er[(size_t)node * 4 + head] = rv;
        }
    }

    // ---- i8 quant, fixed scale: thread = (row=t>>2, quarter=t&3)
    {
        const int r = t >> 2, q = t & 3;
        const int node = nodeBase + r;
        unsigned int outw[8];
#pragma unroll
        for (int j = 0; j < 4; ++j) {
            int ch = r * 16 + q * 4 + j;
            uint4 c4 = *(const uint4*)((const char*)hl + ((ch * 16) ^ ((r & 7) << 4)));
            const __half2* hp = (const __half2*)&c4;
#pragma unroll
            for (int u = 0; u < 2; ++u) {
                float2 fa = __half22float2(hp[2 * u]);
                float2 fb = __half22float2(hp[2 * u + 1]);
                unsigned i0 = (unsigned)(min(max(__float2int_rn(fa.x * QINV), -128), 127) + 128);
                unsigned i1 = (unsigned)(min(max(__float2int_rn(fa.y * QINV), -128), 127) + 128);
                unsigned i2 = (unsigned)(min(max(__float2int_rn(fb.x * QINV), -128), 127) + 128);
                unsigned i3 = (unsigned)(min(max(__float2int_rn(fb.y * QINV), -128), 127) + 128);
                outw[j * 2 + u] = i0 | (i1 << 8) | (i2 << 16) | (i3 << 24);
            }
        }
        if (node < N) {
            uint4* d4 = (uint4*)(feat8 + (size_t)node * 128 + q * 32);
            d4[0] = make_uint4(outw[0], outw[1], outw[2], outw[3]);
            d4[1] = make_uint4(outw[4], outw[5], outw[6], outw[7]);
        }
    }
}

// ---------------------------------------------------------------------------
// Kernel 2: edge weights, head-major streams (single stream, r7 form).
// ---------------------------------------------------------------------------
__global__ __launch_bounds__(256) void edgew_kernel(
    const float* __restrict__ el, const float* __restrict__ er,
    const int* __restrict__ src, const int* __restrict__ dst,
    __half* __restrict__ w_t, int E)
{
    int e = blockIdx.x * 256 + threadIdx.x;
    if (e >= E) return;
    int sv = src[e], dv = dst[e];
    float4 a = *(const float4*)(el + (size_t)sv * 4);
    float4 b = *(const float4*)(er + (size_t)dv * 4);
    float s0 = a.x + b.x, s1 = a.y + b.y, s2 = a.z + b.z, s3 = a.w + b.w;
    s0 = s0 > 0.f ? s0 : NEG_SLOPE * s0;
    s1 = s1 > 0.f ? s1 : NEG_SLOPE * s1;
    s2 = s2 > 0.f ? s2 : NEG_SLOPE * s2;
    s3 = s3 > 0.f ? s3 : NEG_SLOPE * s3;
    w_t[e]                 = __float2half(__expf(s0));
    w_t[(size_t)E + e]     = __float2half(__expf(s1));
    w_t[(size_t)2 * E + e] = __float2half(__expf(s2));
    w_t[(size_t)3 * E + e] = __float2half(__expf(s3));
}

// ---------------------------------------------------------------------------
// Kernel 3: aggregate on biased-i8 feat, r7's exact loop shape (SGPR src,
// single w-stream, 3 fdot2/pair). Byte b=q+128; (0x6600|b) = fp16 1536+b
// = 1664+q exact, so ax = sum(w*(1664+q)); rst = SCALE_G*(ax/dn - 1664)+bias.
// ---------------------------------------------------------------------------
__global__ __launch_bounds__(256) void aggregate_kernel(
    const unsigned char* __restrict__ feat8, const __half* __restrict__ w_t,
    const int* __restrict__ off, const int* __restrict__ src,
    const float* __restrict__ bias, float* __restrict__ out, int N, int E)
{
    const int wid = (int)((blockIdx.x * blockDim.x + threadIdx.x) >> 6);
    const int l = threadIdx.x & 63;
    if (wid >= N) return;
    const int n = __builtin_amdgcn_readfirstlane(wid);   // SGPR node id
    int s = off[n];                                      // s_load
    const int e = off[n + 1];                            // s_load
    const int f0 = 2 * l;
    const int hm = l >> 4;
    const float b0 = bias[f0], b1 = bias[f0 + 1];
    float* outp = out + (size_t)n * 128;
    if (s >= e) {
        outp[f0] = fmaxf(b0, 0.f);
        outp[f0 + 1] = fmaxf(b1, 0.f);
        return;
    }

    const __half* wp = w_t + (size_t)hm * E;
    float ax = 0.f, ay = 0.f, dn = 0.f;
    const unsigned int one2 = 0x3C003C00u;
    const unsigned int bias2 = 0x66006600u;

    if (s & 1) {                                         // align w-stream to dword
        unsigned int gg = *(const unsigned short*)(feat8 + (size_t)src[s] * 128 + f0);
        float w = __half2float(wp[s]);
        ax += w * (float)(1536 + (gg & 0xFF));
        ay += w * (float)(1536 + (gg >> 8));
        dn += w;
        ++s;
    }

    int ei = s;
    for (; ei + 16 <= e; ei += 16) {
        int sv[16];
#pragma unroll
        for (int k = 0; k < 16; ++k) sv[k] = src[ei + k];        // s_loads
        unsigned int w2[8];
#pragma unroll
        for (int k = 0; k < 8; ++k) w2[k] = *(const unsigned int*)(wp + ei + 2 * k);
        unsigned int g[16];
#pragma unroll
        for (int k = 0; k < 16; ++k)
            g[k] = *(const unsigned short*)(feat8 + (size_t)sv[k] * 128 + f0);
#pragma unroll
        for (int k = 0; k < 8; ++k) {
            unsigned int comb = g[2 * k] | (g[2 * k + 1] << 16);
            unsigned int ux = (comb & 0x00FF00FFu) | bias2;
            unsigned int uy = ((comb >> 8) & 0x00FF00FFu) | bias2;
            ax = fdot2f(w2[k], ux, ax);
            ay = fdot2f(w2[k], uy, ay);
            dn = fdot2f(w2[k], one2, dn);
        }
    }
    if (ei + 8 <= e) {
        int sv[8];
#pragma unroll
        for (int k = 0; k < 8; ++k) sv[k] = src[ei + k];
        unsigned int w2[4];
#pragma unroll
        for (int k = 0; k < 4; ++k) w2[k] = *(const unsigned int*)(wp + ei + 2 * k);
        unsigned int g[8];
#pragma unroll
        for (int k = 0; k < 8; ++k)
            g[k] = *(const unsigned short*)(feat8 + (size_t)sv[k] * 128 + f0);
#pragma unroll
        for (int k = 0; k < 4; ++k) {
            unsigned int comb = g[2 * k] | (g[2 * k + 1] << 16);
            unsigned int ux = (comb & 0x00FF00FFu) | bias2;
            unsigned int uy = ((comb >> 8) & 0x00FF00FFu) | bias2;
            ax = fdot2f(w2[k], ux, ax);
            ay = fdot2f(w2[k], uy, ay);
            dn = fdot2f(w2[k], one2, dn);
        }
        ei += 8;
    }
    if (ei + 4 <= e) {
        int sv0 = src[ei], sv1 = src[ei + 1], sv2 = src[ei + 2], sv3 = src[ei + 3];
        unsigned int w2a = *(const unsigned int*)(wp + ei);
        unsigned int w2b = *(const unsigned int*)(wp + ei + 2);
        unsigned int g0 = *(const unsigned short*)(feat8 + (size_t)sv0 * 128 + f0);
        unsigned int g1 = *(const unsigned short*)(feat8 + (size_t)sv1 * 128 + f0);
        unsigned int g2 = *(const unsigned short*)(feat8 + (size_t)sv2 * 128 + f0);
        unsigned int g3 = *(const unsigned short*)(feat8 + (size_t)sv3 * 128 + f0);
        unsigned int comb = g0 | (g1 << 16);
        unsigned int ux = (comb & 0x00FF00FFu) | bias2;
        unsigned int uy = ((comb >> 8) & 0x00FF00FFu) | bias2;
        ax = fdot2f(w2a, ux, ax); ay = fdot2f(w2a, uy, ay); dn = fdot2f(w2a, one2, dn);
        comb = g2 | (g3 << 16);
        ux = (comb & 0x00FF00FFu) | bias2;
        uy = ((comb >> 8) & 0x00FF00FFu) | bias2;
        ax = fdot2f(w2b, ux, ax); ay = fdot2f(w2b, uy, ay); dn = fdot2f(w2b, one2, dn);
        ei += 4;
    }
    for (; ei < e; ++ei) {                               // <=3 tail edges
        unsigned int gg = *(const unsigned short*)(feat8 + (size_t)src[ei] * 128 + f0);
        float w = __half2float(wp[ei]);
        ax += w * (float)(1536 + (gg & 0xFF));
        ay += w * (float)(1536 + (gg >> 8));
        dn += w;
    }
    const float inv = 1.f / dn;
    const float rx = SCALE_G * (ax * inv - 1664.f) + b0;
    const float ry = SCALE_G * (ay * inv - 1664.f) + b1;
    *(float2*)(outp + f0) = make_float2(fmaxf(rx, 0.f), fmaxf(ry, 0.f));
}

// ---------------------------------------------------------------------------
extern "C" void kernel_launch(void* const* d_in, const int* in_sizes, int n_in,
                              void* d_out, int out_size, void* d_ws, size_t ws_size,
                              hipStream_t stream)
{
    const float* h      = (const float*)d_in[0];
    const int*   src    = (const int*)d_in[1];
    const int*   dst    = (const int*)d_in[2];
    const float* W      = (const float*)d_in[3];
    const float* attn_l = (const float*)d_in[4];
    const float* attn_r = (const float*)d_in[5];
    const float* bias   = (const float*)d_in[6];
    const int N = in_sizes[0] / 128;
    const int E = in_sizes[1];
    float* out = (float*)d_out;

    // workspace (all offsets multiples of 16B)
    char* ws = (char*)d_ws;
    unsigned char* feat8 = (unsigned char*)ws; ws += (size_t)N * 128;              // 12.8MB
    float*  el   = (float*)ws;             ws += (size_t)N * 4 * sizeof(float);    // 1.6MB
    float*  er   = (float*)ws;             ws += (size_t)N * 4 * sizeof(float);    // 1.6MB
    __half* w_t  = (__half*)ws;            ws += (size_t)E * 4 * sizeof(__half);   // 12.8MB
    __half* w16t = (__half*)ws;            ws += 128 * 128 * sizeof(__half);       // 32KB
    __half* al16 = (__half*)ws;            ws += 256;
    __half* ar16 = (__half*)ws;            ws += 256;
    int*    off  = (int*)ws;

    hipLaunchKernelGGL(prep_seg_kernel, dim3(64 + (E + 255) / 256), dim3(256), 0, stream,
                       W, w16t, attn_l, attn_r, al16, ar16, dst, off, E, N);
    hipLaunchKernelGGL(proj_kernel, dim3((N + 127) / 128), dim3(512), 0, stream,
                       h, w16t, al16, ar16, feat8, el, er, N);
    hipLaunchKernelGGL(edgew_kernel, dim3((E + 255) / 256), dim3(256), 0, stream,
                       el, er, src, dst, w_t, E);
    hipLaunchKernelGGL(aggregate_kernel, dim3((N + 3) / 4), dim3(256), 0, stream,
                       feat8, w_t, off, src, bias, out, N, E);
}